// Round 6
// baseline (174.353 us; speedup 1.0000x reference)
//
#include <hip/hip_runtime.h>

// Problem constants
#define B_     64
#define L_     1024
#define D_     1280   // 320 float4
#define H1_    640
#define H2_    320
#define NSPLIT 32     // per-batch even-split stripes for pooling
#define KS_    16     // k-splits for mlp1
#define KC_    80     // 1280/16
#define NJT_   10     // j-tiles of 64 cols
#define NBLK2_ 160    // fused kernel blocks (<=256 CUs -> all co-resident)

// ---------------- Kernel 1: per-batch even-split stripe partial sums ----------------
// grid (NSPLIT, B_) = 2048 blocks, 320 threads. Max block work = 32 rows (160 KB),
// finer grain -> dynamic dispatch self-balances CU packing. Block (0,0) also
// zeroes the fused kernel's barrier counters (graph edge makes them visible;
// avoids a memset node — R4 showed tiny fill nodes are pathological).
__global__ void pool_partial(const float* __restrict__ rep, const int* __restrict__ blen,
                             float* __restrict__ part, unsigned int* __restrict__ ctr) {
    const int s   = blockIdx.x;     // stripe
    const int b   = blockIdx.y;     // batch
    const int tid = threadIdx.x;    // 0..319 (float4 lane)

    if (s == 0 && b == 0 && tid == 0) { ctr[0] = 0u; ctr[1] = 0u; }

    const int n  = blen[b] - 2;     // valid rows (>=1)
    const int l0 = 1 + (s * n) / NSPLIT;
    const int l1 = 1 + ((s + 1) * n) / NSPLIT;

    float4 acc = make_float4(0.f, 0.f, 0.f, 0.f);
    const float4* base = (const float4*)rep + (size_t)b * L_ * (D_ / 4) + tid;
    #pragma unroll 4
    for (int l = l0; l < l1; ++l) {
        float4 v = base[(size_t)l * (D_ / 4)];
        acc.x += v.x; acc.y += v.y; acc.z += v.z; acc.w += v.w;
    }
    // always write (empty stripes contribute zeros)
    ((float4*)part)[((size_t)b * NSPLIT + s) * (D_ / 4) + tid] = acc;
}

// ---------------- device barrier (all NBLK2_ blocks resident by construction) ----------
__device__ __forceinline__ void devbar(unsigned int* c, unsigned int target) {
    __syncthreads();
    __threadfence();                               // release my global writes
    if (threadIdx.x == 0) {
        __hip_atomic_fetch_add(c, 1u, __ATOMIC_RELEASE, __HIP_MEMORY_SCOPE_AGENT);
        unsigned int v;
        do {
            __builtin_amdgcn_s_sleep(1);
            v = __hip_atomic_load(c, __ATOMIC_ACQUIRE, __HIP_MEMORY_SCOPE_AGENT);
        } while (v < target);
    }
    __syncthreads();
    __threadfence();                               // acquire other blocks' writes
}

// ---------------- Kernel 2: fused reduce + mlp1 + mlp23 (two device barriers) --------
// 160 blocks x 256 threads.
// Phase A (blocks 0..63): reduce own batch's 32 stripes -> pooled.   [barrier]
// Phase B (all blocks, (jt,ks)): pooled-slice -> LDS, W1 partial -> hpart. [barrier]
// Phase C (blocks 0..63): h-reduce+relu, emb=relu(h@W2+b2)->out, y=emb@W3+b3->out.
__global__ void fused_tail(const float* __restrict__ part, const int* __restrict__ blen,
                           const float* __restrict__ W1, const float* __restrict__ b1,
                           const float* __restrict__ W2, const float* __restrict__ b2,
                           const float* __restrict__ W3, const float* __restrict__ b3,
                           float* __restrict__ pooled, float* __restrict__ hpart,
                           unsigned int* __restrict__ ctr, float* __restrict__ out) {
    const int bid = blockIdx.x;
    const int tid = threadIdx.x;        // 0..255

    // ---- Phase A: stripe reduce for batch b = bid (blocks 0..63) ----
    if (bid < B_) {
        int n = blen[bid] - 2; if (n < 1) n = 1;
        const float inv = 1.0f / (float)n;
        const float4* p = (const float4*)part + (size_t)bid * NSPLIT * (D_ / 4);
        for (int c = tid; c < D_ / 4; c += 256) {
            float4 a = make_float4(0.f, 0.f, 0.f, 0.f);
            #pragma unroll
            for (int s = 0; s < NSPLIT; ++s) {
                float4 v = p[(size_t)s * (D_ / 4) + c];
                a.x += v.x; a.y += v.y; a.z += v.z; a.w += v.w;
            }
            ((float4*)pooled)[(size_t)bid * (D_ / 4) + c] =
                make_float4(a.x * inv, a.y * inv, a.z * inv, a.w * inv);
        }
    }
    devbar(&ctr[0], NBLK2_);

    // ---- Phase B: mlp1 partial, block (jt = bid%10, ks = bid/10) ----
    {
        const int jt = bid % NJT_;
        const int ks = bid / NJT_;
        const int k0 = ks * KC_;
        const int j0 = jt * 64;
        const int jl = tid & 63;
        const int b0 = (tid >> 6) * 16;

        __shared__ float pl[B_][KC_];   // pooled k-slice (20 KB)
        for (int e = tid; e < B_ * (KC_ / 4); e += 256) {
            const int b   = e / (KC_ / 4);
            const int kk4 = e % (KC_ / 4);
            float4 v = ((const float4*)pooled)[(size_t)b * (D_ / 4) + (k0 / 4) + kk4];
            *(float4*)&pl[b][kk4 * 4] = v;
        }
        __syncthreads();

        float acc[16];
        #pragma unroll
        for (int r = 0; r < 16; ++r) acc[r] = 0.f;

        const float* w1p = W1 + (size_t)k0 * H1_ + j0 + jl;
        for (int kk = 0; kk < KC_; kk += 4) {
            const float w0 = w1p[(size_t)(kk + 0) * H1_];
            const float w1 = w1p[(size_t)(kk + 1) * H1_];
            const float w2 = w1p[(size_t)(kk + 2) * H1_];
            const float w3 = w1p[(size_t)(kk + 3) * H1_];
            #pragma unroll
            for (int r = 0; r < 16; ++r) {
                float4 pv = *(const float4*)&pl[b0 + r][kk];
                acc[r] = fmaf(pv.x, w0, acc[r]);
                acc[r] = fmaf(pv.y, w1, acc[r]);
                acc[r] = fmaf(pv.z, w2, acc[r]);
                acc[r] = fmaf(pv.w, w3, acc[r]);
            }
        }
        float* hp = hpart + (size_t)ks * B_ * H1_;
        #pragma unroll
        for (int r = 0; r < 16; ++r)
            hp[(size_t)(b0 + r) * H1_ + j0 + jl] = acc[r];
    }
    devbar(&ctr[1], NBLK2_);
    if (bid >= B_) return;

    // ---- Phase C: mlp23 for batch b = bid ----
    const int b = bid;
    __shared__ float hrow[H1_];
    __shared__ float erow[H2_];

    for (int j = tid; j < H1_; j += 256) {
        float s = b1[j];
        #pragma unroll
        for (int ks = 0; ks < KS_; ++ks)
            s += hpart[((size_t)ks * B_ + b) * H1_ + j];
        hrow[j] = fmaxf(s, 0.f);
    }
    __syncthreads();

    for (int j = tid; j < H2_; j += 256) {
        float s0 = 0.f, s1 = 0.f, s2 = 0.f, s3 = 0.f;
        #pragma unroll 2
        for (int k = 0; k < H1_; k += 4) {
            s0 = fmaf(hrow[k + 0], W2[(size_t)(k + 0) * H2_ + j], s0);
            s1 = fmaf(hrow[k + 1], W2[(size_t)(k + 1) * H2_ + j], s1);
            s2 = fmaf(hrow[k + 2], W2[(size_t)(k + 2) * H2_ + j], s2);
            s3 = fmaf(hrow[k + 3], W2[(size_t)(k + 3) * H2_ + j], s3);
        }
        float s = fmaxf(b2[j] + ((s0 + s1) + (s2 + s3)), 0.f);
        erow[j] = s;
        out[128 + (size_t)b * H2_ + j] = s;
    }
    __syncthreads();

    if (tid < 128) {
        const int o = tid >> 6, lane = tid & 63;
        float s = 0.f;
        for (int j = lane; j < H2_; j += 64)
            s = fmaf(erow[j], W3[(size_t)j * 2 + o], s);
        #pragma unroll
        for (int off = 32; off >= 1; off >>= 1)
            s += __shfl_down(s, off, 64);
        if (lane == 0) out[(size_t)b * 2 + o] = s + b3[o];
    }
}

extern "C" void kernel_launch(void* const* d_in, const int* in_sizes, int n_in,
                              void* d_out, int out_size, void* d_ws, size_t ws_size,
                              hipStream_t stream) {
    const float* rep  = (const float*)d_in[0];
    const int*   blen = (const int*)  d_in[1];
    const float* W1   = (const float*)d_in[2];
    const float* b1   = (const float*)d_in[3];
    const float* W2   = (const float*)d_in[4];
    const float* b2   = (const float*)d_in[5];
    const float* W3   = (const float*)d_in[6];
    const float* b3   = (const float*)d_in[7];
    float* out = (float*)d_out;

    // workspace layout (floats):
    //   part   B_*NSPLIT*D_ = 2,621,440  (10.5 MB)
    //   pooled B_*D_        =    81,920
    //   hpart  KS_*B_*H1_   =   655,360
    //   ctr    2 uints
    float*        ws     = (float*)d_ws;
    float*        part   = ws;
    float*        pooled = part + (size_t)B_ * NSPLIT * D_;
    float*        hpart  = pooled + (size_t)B_ * D_;
    unsigned int* ctr    = (unsigned int*)(hpart + (size_t)KS_ * B_ * H1_);

    pool_partial<<<dim3(NSPLIT, B_), 320, 0, stream>>>(rep, blen, part, ctr);
    fused_tail  <<<NBLK2_, 256, 0, stream>>>(part, blen, W1, b1, W2, b2, W3, b3,
                                             pooled, hpart, ctr, out);
}

// Round 7
// 77.581 us; speedup vs baseline: 2.2474x; 2.2474x over previous
//
#include <hip/hip_runtime.h>

// Problem constants
#define B_     64
#define L_     1024
#define D_     1280   // 320 float4
#define H1_    640
#define H2_    320
#define NSPLIT 32     // per-batch even-split stripes for pooling

// ---------------- Kernel 1: per-batch even-split stripe partial sums ----------------
// grid (NSPLIT, B_) = 2048 blocks, 320 threads. Max block work = 32 rows (160 KB).
// Each block streams a contiguous region of one batch; fully coalesced float4.
__global__ void pool_partial(const float* __restrict__ rep, const int* __restrict__ blen,
                             float* __restrict__ part) {
    const int s   = blockIdx.x;     // stripe
    const int b   = blockIdx.y;     // batch
    const int tid = threadIdx.x;    // 0..319 (float4 lane)
    const int n   = blen[b] - 2;    // valid rows (>=1)

    const int l0 = 1 + (s * n) / NSPLIT;
    const int l1 = 1 + ((s + 1) * n) / NSPLIT;

    float4 acc = make_float4(0.f, 0.f, 0.f, 0.f);
    const float4* base = (const float4*)rep + (size_t)b * L_ * (D_ / 4) + tid;
    #pragma unroll 8
    for (int l = l0; l < l1; ++l) {
        float4 v = base[(size_t)l * (D_ / 4)];
        acc.x += v.x; acc.y += v.y; acc.z += v.z; acc.w += v.w;
    }
    // always write (empty stripes contribute zeros)
    ((float4*)part)[((size_t)b * NSPLIT + s) * (D_ / 4) + tid] = acc;
}

// ---------------- Kernel 2: per-batch fused tail (no barriers, no scratch) ----------
// 64 blocks (one per batch) x 320 threads. Everything stays in LDS:
//   A: pooled row = (sum of 32 stripes)/n              -> prow[1280]
//   B: h   = relu(prow @ W1 + b1)                      -> hrow[640]
//   C: emb = relu(hrow @ W2 + b2)                      -> erow[320] + out
//   D: y   = erow @ W3 + b3                            -> out
// W1 (3.28 MB) is read once per block; 8 blocks/XCD share it via L2.
__global__ void fused_tail(const float* __restrict__ part, const int* __restrict__ blen,
                           const float* __restrict__ W1, const float* __restrict__ b1,
                           const float* __restrict__ W2, const float* __restrict__ b2,
                           const float* __restrict__ W3, const float* __restrict__ b3,
                           float* __restrict__ out) {
    const int b   = blockIdx.x;
    const int tid = threadIdx.x;   // 0..319

    __shared__ float prow[D_];     // 5 KB
    __shared__ float hrow[H1_];    // 2.5 KB
    __shared__ float erow[H2_];    // 1.25 KB

    // ---- Phase A: stripe reduce; thread owns float4 column tid ----
    {
        int n = blen[b] - 2; if (n < 1) n = 1;
        const float inv = 1.0f / (float)n;
        const float4* p = (const float4*)part + (size_t)b * NSPLIT * (D_ / 4) + tid;
        float4 a = make_float4(0.f, 0.f, 0.f, 0.f);
        #pragma unroll
        for (int s = 0; s < NSPLIT; ++s) {
            float4 v = p[(size_t)s * (D_ / 4)];
            a.x += v.x; a.y += v.y; a.z += v.z; a.w += v.w;
        }
        ((float4*)prow)[tid] = make_float4(a.x * inv, a.y * inv, a.z * inv, a.w * inv);
    }
    __syncthreads();

    // ---- Phase B: hrow = relu(prow @ W1 + b1); thread owns cols tid, tid+320 ----
    {
        const int j1 = tid, j2 = tid + 320;
        float s1a = 0.f, s1b = 0.f, s2a = 0.f, s2b = 0.f;
        for (int k = 0; k < D_; k += 4) {
            const float4 pv = *(const float4*)&prow[k];          // wave-uniform broadcast
            const float* w = W1 + (size_t)k * H1_;
            s1a = fmaf(pv.x, w[j1],            s1a);
            s1b = fmaf(pv.y, w[H1_ + j1],      s1b);
            s1a = fmaf(pv.z, w[2 * H1_ + j1],  s1a);
            s1b = fmaf(pv.w, w[3 * H1_ + j1],  s1b);
            s2a = fmaf(pv.x, w[j2],            s2a);
            s2b = fmaf(pv.y, w[H1_ + j2],      s2b);
            s2a = fmaf(pv.z, w[2 * H1_ + j2],  s2a);
            s2b = fmaf(pv.w, w[3 * H1_ + j2],  s2b);
        }
        hrow[j1] = fmaxf(s1a + s1b + b1[j1], 0.f);
        hrow[j2] = fmaxf(s2a + s2b + b1[j2], 0.f);
    }
    __syncthreads();

    // ---- Phase C: erow = relu(hrow @ W2 + b2); thread owns col tid ----
    {
        const int j = tid;
        float a0 = 0.f, a1 = 0.f;
        for (int k = 0; k < H1_; k += 4) {
            const float4 hv = *(const float4*)&hrow[k];
            const float* w = W2 + (size_t)k * H2_ + j;
            a0 = fmaf(hv.x, w[0],        a0);
            a1 = fmaf(hv.y, w[H2_],      a1);
            a0 = fmaf(hv.z, w[2 * H2_],  a0);
            a1 = fmaf(hv.w, w[3 * H2_],  a1);
        }
        const float e = fmaxf(a0 + a1 + b2[j], 0.f);
        erow[j] = e;
        out[128 + (size_t)b * H2_ + j] = e;
    }
    __syncthreads();

    // ---- Phase D: y = erow @ W3 + b3 (two waves, shuffle reduce) ----
    if (tid < 128) {
        const int o = tid >> 6, lane = tid & 63;
        float s = 0.f;
        for (int j = lane; j < H2_; j += 64)
            s = fmaf(erow[j], W3[(size_t)j * 2 + o], s);
        #pragma unroll
        for (int off = 32; off >= 1; off >>= 1)
            s += __shfl_down(s, off, 64);
        if (lane == 0) out[(size_t)b * 2 + o] = s + b3[o];
    }
}

extern "C" void kernel_launch(void* const* d_in, const int* in_sizes, int n_in,
                              void* d_out, int out_size, void* d_ws, size_t ws_size,
                              hipStream_t stream) {
    const float* rep  = (const float*)d_in[0];
    const int*   blen = (const int*)  d_in[1];
    const float* W1   = (const float*)d_in[2];
    const float* b1   = (const float*)d_in[3];
    const float* W2   = (const float*)d_in[4];
    const float* b2   = (const float*)d_in[5];
    const float* W3   = (const float*)d_in[6];
    const float* b3   = (const float*)d_in[7];
    float* out = (float*)d_out;

    // workspace: part = B_*NSPLIT*D_ floats (10.5 MB)
    float* part = (float*)d_ws;

    pool_partial<<<dim3(NSPLIT, B_), 320, 0, stream>>>(rep, blen, part);
    fused_tail  <<<B_, 320, 0, stream>>>(part, blen, W1, b1, W2, b2, W3, b3, out);
}